// Round 4
// baseline (934.939 us; speedup 1.0000x reference)
//
#include <hip/hip_runtime.h>
#include <math.h>

#define NN    16384
#define NB    8
#define HD    128
#define TILE  32
#define HALO  6
#define RWS   44      // TILE + 2*HALO
#define PITCH 132     // fp32 row pitch: 528 B, 16B-aligned; bank stride 132%32=4

// Accumulate acc[i] += X[(r0+i)][0:128] . W[0:128][c]   (X in LDS, W global row-major [*][128])
template<int NR>
__device__ __forceinline__ void vacc(const float* X, int r0,
                                     const float* __restrict__ W, int c, float* acc) {
  for (int k4 = 0; k4 < 32; ++k4) {
    const float* wp = W + (k4 * 4) * HD + c;
    float w0 = wp[0], w1 = wp[HD], w2 = wp[2 * HD], w3 = wp[3 * HD];
#pragma unroll
    for (int i = 0; i < NR; ++i) {
      float4 x = *(const float4*)&X[(r0 + i) * PITCH + k4 * 4];
      acc[i] = fmaf(x.x, w0, acc[i]);
      acc[i] = fmaf(x.y, w1, acc[i]);
      acc[i] = fmaf(x.z, w2, acc[i]);
      acc[i] = fmaf(x.w, w3, acc[i]);
    }
  }
}

__device__ __forceinline__ float silu_acc(float z) {
  return z / (1.0f + expf(-z));   // accurate libm path
}

__global__ __launch_bounds__(256, 2) void gno_valu(
    const float* __restrict__ h, const float* __restrict__ coord,
    const float* __restrict__ msg_w1, const float* __restrict__ msg_b1,
    const float* __restrict__ msg_w2, const float* __restrict__ msg_b2,
    const float* __restrict__ upd_w1, const float* __restrict__ upd_b1,
    const float* __restrict__ upd_w2, const float* __restrict__ upd_b2,
    const float* __restrict__ ln_g, const float* __restrict__ ln_b,
    float* __restrict__ out) {
  __shared__ float sH[RWS * PITCH];   // h fp32, rows = nodes n0-6 .. n0+37 ; live to G4
  __shared__ float sB[RWS * PITCH];   // B (G1->MSG), then agg rows 0..31 (G3->G4)
  __shared__ float sA[TILE * PITCH];  // A (G2->MSG), then t (G4->G5)
  __shared__ float sS[TILE * PITCH];  // s (MSG->G3), then dh (G5->LN)
  __shared__ float sC[RWS];           // coord

  const int t = threadIdx.x;
  const int c = t & 127;              // output column
  const int half = t >> 7;            // 0..1
  const int b = blockIdx.x / (NN / TILE);
  const int n0 = (blockIdx.x % (NN / TILE)) * TILE;
  const size_t hb = ((size_t)b * NN + n0) * HD;

  // ---- stage h + coord (fp32, no conversion), zero-fill OOB halo ----
  for (int e = t; e < RWS * HD; e += 256) {
    int r = e >> 7, cc = e & 127;
    int g = n0 - HALO + r;
    sH[r * PITCH + cc] = (g >= 0 && g < NN) ? h[((size_t)b * NN + g) * HD + cc] : 0.f;
  }
  if (t < RWS) {
    int g = n0 - HALO + t;
    sC[t] = (g >= 0 && g < NN) ? coord[(size_t)b * NN + g] : 0.f;
  }
  __syncthreads();

  // ---- G1: B = sH(44 rows) @ msg_w1[128:256]  -> sB ----
  {
    float acc[22];
#pragma unroll
    for (int i = 0; i < 22; ++i) acc[i] = 0.f;
    const int r0 = half * 22;
    vacc<22>(sH, r0, msg_w1 + 128 * HD, c, acc);
#pragma unroll
    for (int i = 0; i < 22; ++i) sB[(r0 + i) * PITCH + c] = acc[i];
  }
  // ---- G2: A = sH(tile rows) @ msg_w1[0:128] + b1 -> sA ----
  {
    float acc[16];
    float bv = msg_b1[c];
#pragma unroll
    for (int i = 0; i < 16; ++i) acc[i] = bv;
    const int r0 = half * 16;
    vacc<16>(sH, HALO + r0, msg_w1, c, acc);
#pragma unroll
    for (int i = 0; i < 16; ++i) sA[(r0 + i) * PITCH + c] = acc[i];
  }
  __syncthreads();

  // ---- MSG: s_i = (1/cnt) * sum_{d!=0,|d|<=6} silu(A_i + B_{i+d} + (c_j-c_i)*w1_last) ----
  {
    const float wl = msg_w1[256 * HD + c];
    for (int rr = 0; rr < 16; ++rr) {
      const int r = half * 16 + rr;
      const int i = n0 + r;
      const float a = sA[r * PITCH + c];
      const float ci = sC[r + HALO];
      float s = 0.f;
#pragma unroll
      for (int d = -HALO; d <= HALO; ++d) {
        if (d == 0) continue;
        const int j = i + d;
        if (j >= 0 && j < NN) {
          const int rj = r + HALO + d;
          const float z = a + sB[rj * PITCH + c] + (sC[rj] - ci) * wl;
          s += silu_acc(z);
        }
      }
      const int cnt = min(i, HALO) + min(NN - 1 - i, HALO);
      sS[r * PITCH + c] = s / (float)cnt;
    }
  }
  __syncthreads();

  // ---- G3: agg = sS @ msg_w2 + b2 -> sB rows 0..31 (B dead) ----
  {
    float acc[16];
    float bv = msg_b2[c];
#pragma unroll
    for (int i = 0; i < 16; ++i) acc[i] = bv;
    const int r0 = half * 16;
    vacc<16>(sS, r0, msg_w2, c, acc);
    __syncthreads();   // ensure all waves finished reading B before overwrite
#pragma unroll
    for (int i = 0; i < 16; ++i) sB[(r0 + i) * PITCH + c] = acc[i];
  }
  __syncthreads();

  // ---- G4: t = silu(h @ upd_w1[0:128] + agg @ upd_w1[128:256] + ub1) -> sA (A dead) ----
  {
    float acc[16];
    float bv = upd_b1[c];
#pragma unroll
    for (int i = 0; i < 16; ++i) acc[i] = bv;
    const int r0 = half * 16;
    vacc<16>(sH, HALO + r0, upd_w1, c, acc);
    vacc<16>(sB, r0, upd_w1 + 128 * HD, c, acc);
#pragma unroll
    for (int i = 0; i < 16; ++i) sA[(r0 + i) * PITCH + c] = silu_acc(acc[i]);
  }
  __syncthreads();

  // ---- G5: dh = t @ upd_w2 + ub2 -> sS (s dead) ----
  {
    float acc[16];
    float bv = upd_b2[c];
#pragma unroll
    for (int i = 0; i < 16; ++i) acc[i] = bv;
    const int r0 = half * 16;
    vacc<16>(sA, r0, upd_w2, c, acc);
#pragma unroll
    for (int i = 0; i < 16; ++i) sS[(r0 + i) * PITCH + c] = acc[i];
  }
  __syncthreads();

  // ---- LN: x = h + dh; out = (x - mu) * rsqrt(var + eps) * g + b ----
  {
    const int r = t >> 3;       // 0..31
    const int part = t & 7;     // 0..7
    const int c0 = part * 16;
    const float* hrow = h + hb + (size_t)r * HD + c0;
    float xs[16];
    float s1 = 0.f, s2 = 0.f;
#pragma unroll
    for (int q = 0; q < 4; ++q) {
      float4 hv = *(const float4*)(hrow + q * 4);
      float4 dv = *(const float4*)&sS[r * PITCH + c0 + q * 4];
      float x0 = hv.x + dv.x, x1 = hv.y + dv.y, x2 = hv.z + dv.z, x3 = hv.w + dv.w;
      xs[q * 4 + 0] = x0; xs[q * 4 + 1] = x1; xs[q * 4 + 2] = x2; xs[q * 4 + 3] = x3;
      s1 += x0 + x1 + x2 + x3;
      s2 += x0 * x0 + x1 * x1 + x2 * x2 + x3 * x3;
    }
    s1 += __shfl_xor(s1, 1); s2 += __shfl_xor(s2, 1);
    s1 += __shfl_xor(s1, 2); s2 += __shfl_xor(s2, 2);
    s1 += __shfl_xor(s1, 4); s2 += __shfl_xor(s2, 4);
    float mean = s1 * (1.0f / 128.0f);
    float var = s2 * (1.0f / 128.0f) - mean * mean;
    float rstd = rsqrtf(fmaxf(var, 0.f) + 1e-5f);
    float* orow = out + hb + (size_t)r * HD + c0;
#pragma unroll
    for (int q = 0; q < 4; ++q) {
      float4 gv = *(const float4*)(ln_g + c0 + q * 4);
      float4 bv = *(const float4*)(ln_b + c0 + q * 4);
      float4 ov;
      ov.x = (xs[q * 4 + 0] - mean) * rstd * gv.x + bv.x;
      ov.y = (xs[q * 4 + 1] - mean) * rstd * gv.y + bv.y;
      ov.z = (xs[q * 4 + 2] - mean) * rstd * gv.z + bv.z;
      ov.w = (xs[q * 4 + 3] - mean) * rstd * gv.w + bv.w;
      *(float4*)(orow + q * 4) = ov;
    }
  }
}

extern "C" void kernel_launch(void* const* d_in, const int* in_sizes, int n_in,
                              void* d_out, int out_size, void* d_ws, size_t ws_size,
                              hipStream_t stream) {
  const float* h      = (const float*)d_in[0];
  const float* coord  = (const float*)d_in[1];
  const float* msg_w1 = (const float*)d_in[2];
  const float* msg_b1 = (const float*)d_in[3];
  const float* msg_w2 = (const float*)d_in[4];
  const float* msg_b2 = (const float*)d_in[5];
  const float* upd_w1 = (const float*)d_in[6];
  const float* upd_b1 = (const float*)d_in[7];
  const float* upd_w2 = (const float*)d_in[8];
  const float* upd_b2 = (const float*)d_in[9];
  const float* ln_g   = (const float*)d_in[10];
  const float* ln_b   = (const float*)d_in[11];

  gno_valu<<<NB * (NN / TILE), 256, 0, stream>>>(
      h, coord, msg_w1, msg_b1, msg_w2, msg_b2, upd_w1, upd_b1, upd_w2, upd_b2,
      ln_g, ln_b, (float*)d_out);
}

// Round 5
// 921.779 us; speedup vs baseline: 1.0143x; 1.0143x over previous
//
#include <hip/hip_runtime.h>
#include <math.h>

#define NN    16384
#define NB    8
#define HD    128
#define TILE  32
#define HALO  6
#define RWS   44      // TILE + 2*HALO (valid rows)
#define RWSP  48      // padded to 3 m-tiles of 16
#define PITCH 132     // fp32 row pitch: 528 B = 16B-aligned; bank stride 132%32=4

typedef short v8s __attribute__((ext_vector_type(8)));
typedef float v4f __attribute__((ext_vector_type(4)));

__device__ __forceinline__ unsigned short f2b(float x) {
  union { float f; unsigned u; } v; v.f = x;
  unsigned r = v.u + 0x7FFFu + ((v.u >> 16) & 1u);
  return (unsigned short)(r >> 16);
}
__device__ __forceinline__ float b2f(unsigned short u) {
  union { unsigned u; float f; } v; v.u = ((unsigned)u) << 16; return v.f;
}
__device__ __forceinline__ float silu_acc(float z) {
  return z / (1.0f + expf(-z));   // accurate libm path (validated in round 4)
}
// split 8 fp32 -> bf16 hi + bf16 residual lo (x ~= hi + lo, rel err ~2^-17)
__device__ __forceinline__ void split8(const float* p, v8s& hi, v8s& lo) {
#pragma unroll
  for (int j = 0; j < 8; ++j) {
    unsigned short u = f2b(p[j]);
    hi[j] = (short)u;
    lo[j] = (short)f2b(p[j] - b2f(u));
  }
}

// MFMA GEMM, bf16x3 (fp32-quality): acc[mt][nt] += X[MOFF+mt*16+m][:] @ W[:][n]
// X: fp32 in LDS (PITCH row pitch). W: fp32 in GLOBAL, row-major [128][128] (k-major
// rows) -- exactly the layout the B-operand wants, no transpose.
// Wave covers output cols [wave*32, wave*32+32).
template<int MT, int MOFF>
__device__ __forceinline__ void mgemm(const float* X, const float* __restrict__ W,
                                      int wave, int l15, int quad, v4f acc[][2]) {
  const int k0q = quad * 8;
  v8s whi[2][4], wlo[2][4];
#pragma unroll
  for (int nt = 0; nt < 2; ++nt) {
    const int n = wave * 32 + nt * 16 + l15;
#pragma unroll
    for (int ks = 0; ks < 4; ++ks) {
      float wv[8];
#pragma unroll
      for (int j = 0; j < 8; ++j) wv[j] = W[(ks * 32 + k0q + j) * HD + n];
      split8(wv, whi[nt][ks], wlo[nt][ks]);
    }
  }
#pragma unroll
  for (int ks = 0; ks < 4; ++ks) {
#pragma unroll
    for (int mt = 0; mt < MT; ++mt) {
      float xv[8];
      const float* xp = &X[(MOFF + mt * 16 + l15) * PITCH + ks * 32 + k0q];
      *(float4*)&xv[0] = *(const float4*)xp;
      *(float4*)&xv[4] = *(const float4*)(xp + 4);
      v8s ahi, alo;
      split8(xv, ahi, alo);
#pragma unroll
      for (int nt = 0; nt < 2; ++nt) {
        acc[mt][nt] = __builtin_amdgcn_mfma_f32_16x16x32_bf16(ahi, whi[nt][ks], acc[mt][nt], 0, 0, 0);
        acc[mt][nt] = __builtin_amdgcn_mfma_f32_16x16x32_bf16(ahi, wlo[nt][ks], acc[mt][nt], 0, 0, 0);
        acc[mt][nt] = __builtin_amdgcn_mfma_f32_16x16x32_bf16(alo, whi[nt][ks], acc[mt][nt], 0, 0, 0);
      }
    }
  }
}

__global__ __launch_bounds__(256, 2) void gno_mfma(
    const float* __restrict__ h, const float* __restrict__ coord,
    const float* __restrict__ msg_w1, const float* __restrict__ msg_b1,
    const float* __restrict__ msg_w2, const float* __restrict__ msg_b2,
    const float* __restrict__ upd_w1, const float* __restrict__ upd_b1,
    const float* __restrict__ upd_w2, const float* __restrict__ upd_b2,
    const float* __restrict__ ln_g, const float* __restrict__ ln_b,
    float* __restrict__ out) {
  __shared__ float sH[RWSP * PITCH];  // h fp32, rows = nodes n0-6 .. n0+41 (44..47 zero/extra)
  __shared__ float sB[RWSP * PITCH];  // B (G1->MSG), then agg rows 0..31 (G3->G4)
  __shared__ float sA[TILE * PITCH];  // A (G2->MSG), then t (G4->G5)
  __shared__ float sS[TILE * PITCH];  // s (MSG->G3), then dh (G5->LN)
  __shared__ float sC[RWSP];          // coord

  const int t = threadIdx.x;
  const int wave = t >> 6, lane = t & 63, l15 = lane & 15, quad = lane >> 4;
  const int b = blockIdx.x / (NN / TILE);
  const int n0 = (blockIdx.x % (NN / TILE)) * TILE;
  const size_t hb = ((size_t)b * NN + n0) * HD;
  const int col0 = wave * 32 + l15, col1 = col0 + 16;

  // ---- stage h + coord (fp32), zero-fill OOB rows; 48 rows for m-tile alignment ----
  for (int e = t; e < RWSP * HD; e += 256) {
    int r = e >> 7, cc = e & 127;
    int g = n0 - HALO + r;
    sH[r * PITCH + cc] = (g >= 0 && g < NN) ? h[((size_t)b * NN + g) * HD + cc] : 0.f;
  }
  if (t < RWSP) {
    int g = n0 - HALO + t;
    sC[t] = (g >= 0 && g < NN) ? coord[(size_t)b * NN + g] : 0.f;
  }
  __syncthreads();

  // ---- G1 (MFMA): B = sH(48 rows) @ msg_w1[128:256] -> sB ----
  {
    v4f acc[3][2];
#pragma unroll
    for (int mt = 0; mt < 3; ++mt)
#pragma unroll
      for (int nt = 0; nt < 2; ++nt) acc[mt][nt] = (v4f){0.f, 0.f, 0.f, 0.f};
    mgemm<3, 0>(sH, msg_w1 + 128 * HD, wave, l15, quad, acc);
#pragma unroll
    for (int mt = 0; mt < 3; ++mt)
#pragma unroll
      for (int nt = 0; nt < 2; ++nt)
#pragma unroll
        for (int rg = 0; rg < 4; ++rg)
          sB[(mt * 16 + quad * 4 + rg) * PITCH + wave * 32 + nt * 16 + l15] = acc[mt][nt][rg];
  }
  // ---- G2 (MFMA): A = sH(tile rows) @ msg_w1[0:128] + b1 -> sA ----
  {
    v4f acc[2][2];
#pragma unroll
    for (int mt = 0; mt < 2; ++mt)
#pragma unroll
      for (int nt = 0; nt < 2; ++nt) acc[mt][nt] = (v4f){0.f, 0.f, 0.f, 0.f};
    mgemm<2, HALO>(sH, msg_w1, wave, l15, quad, acc);
    float bv0 = msg_b1[col0], bv1 = msg_b1[col1];
#pragma unroll
    for (int mt = 0; mt < 2; ++mt)
#pragma unroll
      for (int nt = 0; nt < 2; ++nt)
#pragma unroll
        for (int rg = 0; rg < 4; ++rg)
          sA[(mt * 16 + quad * 4 + rg) * PITCH + wave * 32 + nt * 16 + l15] =
              acc[mt][nt][rg] + (nt ? bv1 : bv0);
  }
  __syncthreads();

  // ---- MSG (verbatim round 4): s_i = (1/cnt) * sum silu(A_i + B_j + dc*w1_last) ----
  {
    const int c = t & 127;
    const int half = t >> 7;
    const float wl = msg_w1[256 * HD + c];
    for (int rr = 0; rr < 16; ++rr) {
      const int r = half * 16 + rr;
      const int i = n0 + r;
      const float a = sA[r * PITCH + c];
      const float ci = sC[r + HALO];
      float s = 0.f;
#pragma unroll
      for (int d = -HALO; d <= HALO; ++d) {
        if (d == 0) continue;
        const int j = i + d;
        if (j >= 0 && j < NN) {
          const int rj = r + HALO + d;
          const float z = a + sB[rj * PITCH + c] + (sC[rj] - ci) * wl;
          s += silu_acc(z);
        }
      }
      const int cnt = min(i, HALO) + min(NN - 1 - i, HALO);
      sS[r * PITCH + c] = s / (float)cnt;
    }
  }
  __syncthreads();

  // ---- G3 (MFMA): agg = sS @ msg_w2 + b2 -> sB rows 0..31 (B dead) ----
  {
    v4f acc[2][2];
#pragma unroll
    for (int mt = 0; mt < 2; ++mt)
#pragma unroll
      for (int nt = 0; nt < 2; ++nt) acc[mt][nt] = (v4f){0.f, 0.f, 0.f, 0.f};
    mgemm<2, 0>(sS, msg_w2, wave, l15, quad, acc);
    float bv0 = msg_b2[col0], bv1 = msg_b2[col1];
    __syncthreads();
#pragma unroll
    for (int mt = 0; mt < 2; ++mt)
#pragma unroll
      for (int nt = 0; nt < 2; ++nt)
#pragma unroll
        for (int rg = 0; rg < 4; ++rg)
          sB[(mt * 16 + quad * 4 + rg) * PITCH + wave * 32 + nt * 16 + l15] =
              acc[mt][nt][rg] + (nt ? bv1 : bv0);
  }
  __syncthreads();

  // ---- G4 (MFMA): t = silu(sH@upd_w1[0:128] + agg@upd_w1[128:256] + ub1) -> sA ----
  {
    v4f acc[2][2];
#pragma unroll
    for (int mt = 0; mt < 2; ++mt)
#pragma unroll
      for (int nt = 0; nt < 2; ++nt) acc[mt][nt] = (v4f){0.f, 0.f, 0.f, 0.f};
    mgemm<2, HALO>(sH, upd_w1, wave, l15, quad, acc);
    mgemm<2, 0>(sB, upd_w1 + 128 * HD, wave, l15, quad, acc);
    float bv0 = upd_b1[col0], bv1 = upd_b1[col1];
#pragma unroll
    for (int mt = 0; mt < 2; ++mt)
#pragma unroll
      for (int nt = 0; nt < 2; ++nt)
#pragma unroll
        for (int rg = 0; rg < 4; ++rg)
          sA[(mt * 16 + quad * 4 + rg) * PITCH + wave * 32 + nt * 16 + l15] =
              silu_acc(acc[mt][nt][rg] + (nt ? bv1 : bv0));
  }
  __syncthreads();

  // ---- G5 (MFMA): dh = t @ upd_w2 + ub2 -> sS (s dead) ----
  {
    v4f acc[2][2];
#pragma unroll
    for (int mt = 0; mt < 2; ++mt)
#pragma unroll
      for (int nt = 0; nt < 2; ++nt) acc[mt][nt] = (v4f){0.f, 0.f, 0.f, 0.f};
    mgemm<2, 0>(sA, upd_w2, wave, l15, quad, acc);
    float bv0 = upd_b2[col0], bv1 = upd_b2[col1];
#pragma unroll
    for (int mt = 0; mt < 2; ++mt)
#pragma unroll
      for (int nt = 0; nt < 2; ++nt)
#pragma unroll
        for (int rg = 0; rg < 4; ++rg)
          sS[(mt * 16 + quad * 4 + rg) * PITCH + wave * 32 + nt * 16 + l15] =
              acc[mt][nt][rg] + (nt ? bv1 : bv0);
  }
  __syncthreads();

  // ---- LN (verbatim round 4): x = h + dh; out = (x-mu)*rstd*g + b ----
  {
    const int r = t >> 3;       // 0..31
    const int part = t & 7;     // 0..7
    const int c0 = part * 16;
    const float* hrow = h + hb + (size_t)r * HD + c0;
    float xs[16];
    float s1 = 0.f, s2 = 0.f;
#pragma unroll
    for (int q = 0; q < 4; ++q) {
      float4 hv = *(const float4*)(hrow + q * 4);
      float4 dv = *(const float4*)&sS[r * PITCH + c0 + q * 4];
      float x0 = hv.x + dv.x, x1 = hv.y + dv.y, x2 = hv.z + dv.z, x3 = hv.w + dv.w;
      xs[q * 4 + 0] = x0; xs[q * 4 + 1] = x1; xs[q * 4 + 2] = x2; xs[q * 4 + 3] = x3;
      s1 += x0 + x1 + x2 + x3;
      s2 += x0 * x0 + x1 * x1 + x2 * x2 + x3 * x3;
    }
    s1 += __shfl_xor(s1, 1); s2 += __shfl_xor(s2, 1);
    s1 += __shfl_xor(s1, 2); s2 += __shfl_xor(s2, 2);
    s1 += __shfl_xor(s1, 4); s2 += __shfl_xor(s2, 4);
    float mean = s1 * (1.0f / 128.0f);
    float var = s2 * (1.0f / 128.0f) - mean * mean;
    float rstd = rsqrtf(fmaxf(var, 0.f) + 1e-5f);
    float* orow = out + hb + (size_t)r * HD + c0;
#pragma unroll
    for (int q = 0; q < 4; ++q) {
      float4 gv = *(const float4*)(ln_g + c0 + q * 4);
      float4 bv = *(const float4*)(ln_b + c0 + q * 4);
      float4 ov;
      ov.x = (xs[q * 4 + 0] - mean) * rstd * gv.x + bv.x;
      ov.y = (xs[q * 4 + 1] - mean) * rstd * gv.y + bv.y;
      ov.z = (xs[q * 4 + 2] - mean) * rstd * gv.z + bv.z;
      ov.w = (xs[q * 4 + 3] - mean) * rstd * gv.w + bv.w;
      *(float4*)(orow + q * 4) = ov;
    }
  }
}

extern "C" void kernel_launch(void* const* d_in, const int* in_sizes, int n_in,
                              void* d_out, int out_size, void* d_ws, size_t ws_size,
                              hipStream_t stream) {
  const float* h      = (const float*)d_in[0];
  const float* coord  = (const float*)d_in[1];
  const float* msg_w1 = (const float*)d_in[2];
  const float* msg_b1 = (const float*)d_in[3];
  const float* msg_w2 = (const float*)d_in[4];
  const float* msg_b2 = (const float*)d_in[5];
  const float* upd_w1 = (const float*)d_in[6];
  const float* upd_b1 = (const float*)d_in[7];
  const float* upd_w2 = (const float*)d_in[8];
  const float* upd_b2 = (const float*)d_in[9];
  const float* ln_g   = (const float*)d_in[10];
  const float* ln_b   = (const float*)d_in[11];

  gno_mfma<<<NB * (NN / TILE), 256, 0, stream>>>(
      h, coord, msg_w1, msg_b1, msg_w2, msg_b2, upd_w1, upd_b1, upd_w2, upd_b2,
      ln_g, ln_b, (float*)d_out);
}